// Round 14
// baseline (102.810 us; speedup 1.0000x reference)
//
#include <hip/hip_runtime.h>
#include <hip/hip_bf16.h>
#include <stdint.h>

// Problem constants (B=2, S=2048, IN=4096, OUT=4096)
#define MDIM 4096   // B*S
#define NDIM 4096   // OUT
#define KDIM 4096   // IN
#define NT   (KDIM / 64)   // 64 K-tiles of 64 i8 elements

typedef __attribute__((ext_vector_type(4)))  float f32x4;
typedef __attribute__((ext_vector_type(4)))  int   i32x4;
typedef __attribute__((ext_vector_type(16))) int   i32x16;
typedef __attribute__((ext_vector_type(8)))  short bf16x8;
typedef __attribute__((ext_vector_type(4)))  float fx4;
typedef __attribute__((ext_vector_type(4)))  int   ix4;
typedef __attribute__((ext_vector_type(8)))  unsigned short usx8;

__device__ static inline unsigned short f32_to_bf16_rne(float f) {
  union { float f; unsigned int u; } v; v.f = f;
  unsigned int u = v.u;
  u += 0x7fffu + ((u >> 16) & 1u);
  return (unsigned short)(u >> 16);
}

__device__ static inline void gload_lds16(const void* g, void* l) {
  __builtin_amdgcn_global_load_lds((const __attribute__((address_space(1))) void*)g,
                                   (__attribute__((address_space(3))) void*)l,
                                   16, 0, 0);
}

// 32x32x32 i8 MFMA via inline asm (D==C via "+v"); register deps give the
// compiler exact counted lgkmcnt insertion for LDS-sourced operands.
__device__ static inline void mfma_i8_32(i32x16& d, const i32x4& a, const i32x4& b) {
  asm("v_mfma_i32_32x32x32_i8 %0, %1, %2, %0" : "+v"(d) : "v"(a), "v"(b));
}

// ---------------- prepass: quantize x (per-row) + pack w ----------------
// (unchanged from R8/R13 validated artifact)

__global__ __launch_bounds__(256) void quant_both(
    const float* __restrict__ x, const int* __restrict__ w8,
    signed char* __restrict__ xq, signed char* __restrict__ wq,
    float* __restrict__ xs) {
  const int bid = blockIdx.x, t = threadIdx.x;
  if (bid < MDIM) {
    const float* row = x + (size_t)bid * KDIM + t * 16;
    fx4 v0 = *(const fx4*)(row);
    fx4 v1 = *(const fx4*)(row + 4);
    fx4 v2 = *(const fx4*)(row + 8);
    fx4 v3 = *(const fx4*)(row + 12);
    float am = 0.0f;
#pragma unroll
    for (int j = 0; j < 4; ++j) {
      am = fmaxf(am, fmaxf(__builtin_fabsf(v0[j]), __builtin_fabsf(v1[j])));
      am = fmaxf(am, fmaxf(__builtin_fabsf(v2[j]), __builtin_fabsf(v3[j])));
    }
#pragma unroll
    for (int off = 32; off; off >>= 1) am = fmaxf(am, __shfl_xor(am, off));
    __shared__ float wm[4];
    if ((t & 63) == 0) wm[t >> 6] = am;
    __syncthreads();
    am = fmaxf(fmaxf(wm[0], wm[1]), fmaxf(wm[2], wm[3]));
    am = fmaxf(am, 1e-20f);
    const float qs = 127.0f / am;
    int q[16];
#pragma unroll
    for (int j = 0; j < 4; ++j) {
      q[j]      = (int)rintf(v0[j] * qs);
      q[4 + j]  = (int)rintf(v1[j] * qs);
      q[8 + j]  = (int)rintf(v2[j] * qs);
      q[12 + j] = (int)rintf(v3[j] * qs);
    }
    i32x4 pk;
#pragma unroll
    for (int j = 0; j < 4; ++j)
      pk[j] = (q[4*j] & 255) | ((q[4*j+1] & 255) << 8) |
              ((q[4*j+2] & 255) << 16) | ((q[4*j+3] & 255) << 24);
    *(i32x4*)(xq + (size_t)bid * KDIM + t * 16) = pk;
    if (t == 0) xs[bid] = am * (1.0f / 127.0f);
  } else {
    const int n = bid - MDIM;
    const int* row = w8 + (size_t)n * KDIM + t * 16;
    ix4 w0 = *(const ix4*)(row);
    ix4 w1 = *(const ix4*)(row + 4);
    ix4 w2 = *(const ix4*)(row + 8);
    ix4 w3 = *(const ix4*)(row + 12);
    i32x4 pk;
    pk[0] = (w0[0] & 255) | ((w0[1] & 255) << 8) | ((w0[2] & 255) << 16) | ((w0[3] & 255) << 24);
    pk[1] = (w1[0] & 255) | ((w1[1] & 255) << 8) | ((w1[2] & 255) << 16) | ((w1[3] & 255) << 24);
    pk[2] = (w2[0] & 255) | ((w2[1] & 255) << 8) | ((w2[2] & 255) << 16) | ((w2[3] & 255) << 24);
    pk[3] = (w3[0] & 255) | ((w3[1] & 255) << 8) | ((w3[2] & 255) << 16) | ((w3[3] & 255) << 24);
    *(i32x4*)(wq + (size_t)n * KDIM + t * 16) = pk;
  }
}

// ---------------- 256x256 int8 GEMM: R8 skeleton + 32x32x32 MFMA ----------------
// IDENTICAL to the validated R8/R13 artifact in: staging (4 gloads/tile,
// pre-swizzled source, lane-linear dest), vmcnt ledger (VM4 steady, VM0 at
// NT-2), barrier placement, grid (256 x 512thr), LDS (2x 32 KiB).
// ONLY the MFMA shape / fragment addressing / epilogue mapping change.
//
// v_mfma_i32_32x32x32_i8: A/B = 4 regs (16 i8, K=32 slice): lane l holds
//   row l&31, k = 16*(l>>5)+j  [analog of the R8-validated 16x16x64 rule].
// C/D (m74/m101, dtype-independent): col = lane&31,
//   row = (reg&3) + 8*(reg>>2) + 4*(lane>>5), reg 0..15.
// Wave tile 128x64 = 4 row-blocks x 2 col-blocks; K=64 tile = 2 k-halves.
//   a0/b0 = kh0 fragments, a1/b1 = kh1. 8 MFMAs per phase.
// Tile schedule (R8's, reads one-phase-ahead):
//   [boundary: read a0(4),b0(2) kh0 from cur]
//   Phase A: read a1(4),b1(2) kh1; 8 MFMA kh0 (a0 x b0); LGKM0; BAR
//   Phase B: stage tile u+2 (4 gloads); 8 MFMA kh1 (a1 x b1);
//            VM4; BAR; read-ahead a0,b0 from nxt
// Region safety ledger == R8 (all 12 ds_reads of cur drained at Phase-A
//   LGKM0+BAR before any stage into cur; cur re-read at u+2 gated by u+1's
//   VM4+BAR). vmcnt ledger == R8.
// LDS slot math: LDS[row][s] = global[row][s ^ ((row>>1)&3)] (R8 staging,
//   verified 0 conflicts). Desired global slot for kh,hi = kh*2+hi ->
//   read slot = (kh*2+hi) ^ ((fr32>>1)&3). Per-16-lane groups: 8 bank-runs
//   x 2 lanes = 2-way (free), same as validated.

__global__ __launch_bounds__(512, 2) void gemm_i8(
    const signed char* __restrict__ Aq,    // [M][K] i8
    const signed char* __restrict__ Wq,    // [N][K] i8
    const float* __restrict__ xs,          // [M] row scale = absmax/127
    const float* __restrict__ scales,      // [N]
    const float* __restrict__ bias,
    float* __restrict__ C) {
  __shared__ signed char Ash[2 * 16384];   // [2][256][64]
  __shared__ signed char Bsh[2 * 16384];

  const int tid = threadIdx.x;
  const int w    = tid >> 6;
  const int l    = tid & 63;
  const int wr   = w >> 2;           // 0..1 : M half (128 rows)
  const int wc   = w & 3;            // 0..3 : N quarter (64 cols)
  const int fr32 = l & 31;           // row within a 32-block
  const int hi   = l >> 5;           // k-granule within a k-half

  // XCD-aware swizzle: 256 blocks, 256 % 8 == 0
  const int id  = blockIdx.x;
  const int swz = (id & 7) * 32 + (id >> 3);
  const int bm  = swz >> 4, bn = swz & 15;

  const signed char* aorg = Aq + (size_t)(bm * 256) * KDIM;
  const signed char* borg = Wq + (size_t)(bn * 256) * KDIM;

  // staging (VALIDATED, unchanged): wave covers 16 rows of 64B per gload;
  // pre-swizzled global 16B slot; lane-linear LDS dest.
  const int lr = l >> 2;                       // row-in-wave-chunk 0..15
  const int ks = (l & 3) ^ ((l >> 3) & 3);     // swizzled 16B slot
  const size_t g_off = (size_t)(w * 16 + lr) * KDIM + (size_t)ks * 16;
  const int    s_off = w * 1024;               // bytes, wave-uniform

#define STAGE(isB, t, h) do {                                                   \
    const signed char* _g = ((isB) ? borg : aorg)                               \
        + (size_t)(h) * 128 * KDIM + (size_t)(t) * 64 + g_off;                  \
    signed char* _l = ((isB) ? Bsh : Ash)                                       \
        + (((t) & 1) * 16384 + (h) * 8192 + s_off);                             \
    gload_lds16(_g, _l);                                                        \
  } while (0)

  // fragment read addressing (32x32 shape):
  // A row-block rb: row = wr*128 + rb*32 + fr32 ; B col-block cb: wc*64+cb*32+fr32
  // slot for (kh,hi): ((kh*2+hi) ^ ((fr32>>1)&3)) * 16
  const int sw3   = (fr32 >> 1) & 3;
  const int sl_k0 = ((0 + hi) ^ sw3) * 16;
  const int sl_k1 = ((2 + hi) ^ sw3) * 16;
  const int arow  = (wr * 128 + fr32) * 64;    // + rb*2048
  const int brow  = (wc * 64  + fr32) * 64;    // + cb*2048

#define BAR   __builtin_amdgcn_s_barrier()
#define LGKM0 asm volatile("s_waitcnt lgkmcnt(0)" ::: "memory")
#define VM4   asm volatile("s_waitcnt vmcnt(4)" ::: "memory")
#define VM0   asm volatile("s_waitcnt vmcnt(0)" ::: "memory")
#define NOVM  ((void)0)
#define SP1   __builtin_amdgcn_s_setprio(1)
#define SP0   __builtin_amdgcn_s_setprio(0)

  i32x16 acc[4][2] = {};
  i32x4 a0[4], a1[4], b0[2], b1[2];

#define READ_A0(CO) { _Pragma("unroll") for (int rb = 0; rb < 4; ++rb) a0[rb] = *(const i32x4*)(Ash + (CO) + arow + rb * 2048 + sl_k0); }
#define READ_A1(CO) { _Pragma("unroll") for (int rb = 0; rb < 4; ++rb) a1[rb] = *(const i32x4*)(Ash + (CO) + arow + rb * 2048 + sl_k1); }
#define READ_B0(CO) { _Pragma("unroll") for (int cb = 0; cb < 2; ++cb) b0[cb] = *(const i32x4*)(Bsh + (CO) + brow + cb * 2048 + sl_k0); }
#define READ_B1(CO) { _Pragma("unroll") for (int cb = 0; cb < 2; ++cb) b1[cb] = *(const i32x4*)(Bsh + (CO) + brow + cb * 2048 + sl_k1); }

#define MFMA_KH(AA, BB)                                                         \
  { _Pragma("unroll") for (int rb = 0; rb < 4; ++rb)                            \
    _Pragma("unroll") for (int cb = 0; cb < 2; ++cb)                            \
      mfma_i8_32(acc[rb][cb], AA[rb], BB[cb]); }

#define TILE(U, CO, NX, S2, VMST) do {                                          \
    const int _nx = (CO) ^ 16384;                                               \
    /* Phase A: pre-read kh1 frags ; 8 MFMA kh0 */                              \
    READ_B1(CO); READ_A1(CO);                                                   \
    SP1; MFMA_KH(a0, b0); SP0;                                                  \
    LGKM0; BAR;                                                                 \
    /* Phase B: stage (U+2) into cur ; 8 MFMA kh1 */                            \
    if (S2) { STAGE(0, (U) + 2, 0); STAGE(0, (U) + 2, 1);                       \
              STAGE(1, (U) + 2, 0); STAGE(1, (U) + 2, 1); }                     \
    SP1; MFMA_KH(a1, b1); SP0;                                                  \
    VMST; BAR;                                                                  \
    if (NX) { READ_A0(_nx); READ_B0(_nx); }                                     \
  } while (0)

  // ---- prologue: stage t0 + t1 (8 gloads), land t0, boundary read ----
  STAGE(0, 0, 0); STAGE(0, 0, 1); STAGE(1, 0, 0); STAGE(1, 0, 1);
  STAGE(0, 1, 0); STAGE(0, 1, 1); STAGE(1, 1, 0); STAGE(1, 1, 1);
  VM4;   // t0 landed; t1's 4 in flight = steady-state entry
  BAR;
  READ_A0(0); READ_B0(0);

#pragma unroll 2
  for (int u = 0; u < NT - 2; ++u) {
    const int cur = (u & 1) * 16384;
    TILE(u, cur, 1, 1, VM4);
  }
  TILE(NT - 2, 0,     1, 0, VM0);
  TILE(NT - 1, 16384, 0, 0, NOVM);

#undef TILE
#undef MFMA_KH
#undef READ_A0
#undef READ_A1
#undef READ_B0
#undef READ_B1
#undef STAGE

  // ---- epilogue: out = acc * xs[m] * (scales[n]/127) + bias[n] ----
  // C/D: col = l&31, row = (r&3) + 8*(r>>2) + 4*hi (within 32-block)
  const float inv127 = 1.0f / 127.0f;
  const int m_base = bm * 256 + wr * 128;
  const int n_base = bn * 256 + wc * 64;
  float swv[2], bzv[2];
  int   nv[2];
#pragma unroll
  for (int cb = 0; cb < 2; ++cb) {
    nv[cb]  = n_base + cb * 32 + fr32;
    swv[cb] = scales[nv[cb]] * inv127;
    bzv[cb] = bias[nv[cb]];
  }
#pragma unroll
  for (int rb = 0; rb < 4; ++rb) {
    float xr[16];
#pragma unroll
    for (int r = 0; r < 16; ++r)
      xr[r] = xs[m_base + rb * 32 + (r & 3) + 8 * (r >> 2) + 4 * hi];
#pragma unroll
    for (int cb = 0; cb < 2; ++cb) {
#pragma unroll
      for (int r = 0; r < 16; ++r) {
        const int m = m_base + rb * 32 + (r & 3) + 8 * (r >> 2) + 4 * hi;
        C[(size_t)m * NDIM + nv[cb]] = (float)acc[rb][cb][r] * (xr[r] * swv[cb]) + bzv[cb];
      }
    }
  }
}

// ---------------- fallback: fused conversion, reg staging (128^2 bf16) ----------------

__global__ __launch_bounds__(256) void gemm_fused(
    const float* __restrict__ X,
    const int* __restrict__ W,
    const float* __restrict__ scales,
    const float* __restrict__ bias,
    float* __restrict__ C) {
  __shared__ unsigned short As[128 * 32];
  __shared__ unsigned short Bs[128 * 32];

  const int tid = threadIdx.x;
  const int lane = tid & 63;
  const int wave = tid >> 6;
  const int wr = wave >> 1, wc = wave & 1;
  const int fr = lane & 15, fq = lane >> 4;

  int id = blockIdx.x;
  int swz = (id & 7) * 128 + (id >> 3);
  const int bm = swz >> 5, bn = swz & 31;

  const int r0 = tid >> 2;
  const int kc = (tid & 3) * 8;
  const size_t aBase = (size_t)(bm * 128 + r0) * KDIM + kc;
  const size_t bBase = (size_t)(bn * 128 + r0) * KDIM + kc;

  f32x4 acc[4][4] = {};

  for (int k0 = 0; k0 < KDIM; k0 += 32) {
    const float* xp = X + aBase + k0;
    const int*   wp = W + bBase + k0;
    fx4 x0 = *(const fx4*)xp;
    fx4 x1 = *(const fx4*)(xp + 4);
    fx4 x2 = *(const fx4*)(xp + (size_t)64 * KDIM);
    fx4 x3 = *(const fx4*)(xp + (size_t)64 * KDIM + 4);
    ix4 w0 = *(const ix4*)wp;
    ix4 w1 = *(const ix4*)(wp + 4);
    ix4 w2 = *(const ix4*)(wp + (size_t)64 * KDIM);
    ix4 w3 = *(const ix4*)(wp + (size_t)64 * KDIM + 4);

    usx8 ca, cb, cc, cd;
#pragma unroll
    for (int j = 0; j < 4; ++j) {
      ca[j] = f32_to_bf16_rne(x0[j]);  ca[j + 4] = f32_to_bf16_rne(x1[j]);
      cb[j] = f32_to_bf16_rne(x2[j]);  cb[j + 4] = f32_to_bf16_rne(x3[j]);
      cc[j] = f32_to_bf16_rne((float)w0[j]); cc[j + 4] = f32_to_bf16_rne((float)w1[j]);
      cd[j] = f32_to_bf16_rne((float)w2[j]); cd[j + 4] = f32_to_bf16_rne((float)w3[j]);
    }

    __syncthreads();
    *reinterpret_cast<usx8*>(As + tid * 8)        = ca;
    *reinterpret_cast<usx8*>(As + 2048 + tid * 8) = cb;
    *reinterpret_cast<usx8*>(Bs + tid * 8)        = cc;
    *reinterpret_cast<usx8*>(Bs + 2048 + tid * 8) = cd;
    __syncthreads();

    bf16x8 af[4], bfr[4];
    const unsigned short* ap = As + (wr * 64 + fr) * 32 + fq * 8;
    const unsigned short* bp = Bs + (wc * 64 + fr) * 32 + fq * 8;
#pragma unroll
    for (int i = 0; i < 4; ++i) {
      af[i]  = *reinterpret_cast<const bf16x8*>(ap + i * 512);
      bfr[i] = *reinterpret_cast<const bf16x8*>(bp + i * 512);
    }
#pragma unroll
    for (int im = 0; im < 4; ++im)
#pragma unroll
      for (int in_ = 0; in_ < 4; ++in_)
        acc[im][in_] = __builtin_amdgcn_mfma_f32_16x16x32_bf16(
            af[im], bfr[in_], acc[im][in_], 0, 0, 0);
  }

  const float inv127 = 1.0f / 127.0f;
#pragma unroll
  for (int in_ = 0; in_ < 4; ++in_) {
    int n = bn * 128 + wc * 64 + in_ * 16 + fr;
    float sc = scales[n] * inv127;
    float bz = bias[n];
#pragma unroll
    for (int im = 0; im < 4; ++im) {
      int m0 = bm * 128 + wr * 64 + im * 16 + fq * 4;
      float* cp = C + (size_t)m0 * NDIM + n;
#pragma unroll
      for (int r = 0; r < 4; ++r)
        cp[(size_t)r * NDIM] = acc[im][in_][r] * sc + bz;
    }
  }
}

// ---------------- host launch ----------------

extern "C" void kernel_launch(void* const* d_in, const int* in_sizes, int n_in,
                              void* d_out, int out_size, void* d_ws, size_t ws_size,
                              hipStream_t stream) {
  const float* x      = (const float*)d_in[0];
  const int*   w8     = (const int*)d_in[1];
  const float* scales = (const float*)d_in[2];
  // d_in[3] = weight_fp : unused by the reference
  const float* bias   = (const float*)d_in[4];
  float* out = (float*)d_out;

  const size_t xq_bytes = (size_t)MDIM * KDIM;           // 16.7 MB
  const size_t wq_bytes = (size_t)NDIM * KDIM;           // 16.7 MB
  const size_t xs_bytes = (size_t)MDIM * sizeof(float);
  const size_t need = xq_bytes + wq_bytes + xs_bytes;

  if (ws_size >= need) {
    signed char* xq = (signed char*)d_ws;
    signed char* wq = xq + xq_bytes;
    float*       xs = (float*)(wq + wq_bytes);
    quant_both<<<MDIM + NDIM, 256, 0, stream>>>(x, w8, xq, wq, xs);
    gemm_i8<<<256, 512, 0, stream>>>(xq, wq, xs, scales, bias, out);
  } else {
    gemm_fused<<<1024, 256, 0, stream>>>(x, w8, scales, bias, out);
  }
}

// Round 15
// 95.004 us; speedup vs baseline: 1.0822x; 1.0822x over previous
//
#include <hip/hip_runtime.h>
#include <hip/hip_bf16.h>
#include <stdint.h>

// Problem constants (B=2, S=2048, IN=4096, OUT=4096)
#define MDIM 4096   // B*S
#define NDIM 4096   // OUT
#define KDIM 4096   // IN
#define NT   (KDIM / 64)   // 64 K-tiles of 64 i8 elements

typedef __attribute__((ext_vector_type(4))) float  f32x4;
typedef __attribute__((ext_vector_type(4))) int    i32x4;
typedef __attribute__((ext_vector_type(8))) short  bf16x8;
typedef __attribute__((ext_vector_type(4))) float  fx4;
typedef __attribute__((ext_vector_type(4))) int    ix4;
typedef __attribute__((ext_vector_type(8))) unsigned short usx8;

__device__ static inline unsigned short f32_to_bf16_rne(float f) {
  union { float f; unsigned int u; } v; v.f = f;
  unsigned int u = v.u;
  u += 0x7fffu + ((u >> 16) & 1u);
  return (unsigned short)(u >> 16);
}

__device__ static inline void gload_lds16(const void* g, void* l) {
  __builtin_amdgcn_global_load_lds((const __attribute__((address_space(1))) void*)g,
                                   (__attribute__((address_space(3))) void*)l,
                                   16, 0, 0);
}

// i8 MFMA via inline asm (D,A,B,C; D==C via "+v"). Register deps give the
// compiler exact lgkmcnt insertion for LDS-sourced operands.
__device__ static inline void mfma_i8(i32x4& d, const i32x4& a, const i32x4& b) {
  asm("v_mfma_i32_16x16x64_i8 %0, %1, %2, %0" : "+v"(d) : "v"(a), "v"(b));
}

// ---------------- prepass: quantize x (per-row) + pack w ----------------
// blocks 0..MDIM-1: x row -> absmax -> int8, xs[m] = absmax/127
// blocks MDIM..MDIM+NDIM-1: w row (int32 0..126) -> int8 pack

__global__ __launch_bounds__(256) void quant_both(
    const float* __restrict__ x, const int* __restrict__ w8,
    signed char* __restrict__ xq, signed char* __restrict__ wq,
    float* __restrict__ xs) {
  const int bid = blockIdx.x, t = threadIdx.x;
  if (bid < MDIM) {
    const float* row = x + (size_t)bid * KDIM + t * 16;
    fx4 v0 = *(const fx4*)(row);
    fx4 v1 = *(const fx4*)(row + 4);
    fx4 v2 = *(const fx4*)(row + 8);
    fx4 v3 = *(const fx4*)(row + 12);
    float am = 0.0f;
#pragma unroll
    for (int j = 0; j < 4; ++j) {
      am = fmaxf(am, fmaxf(__builtin_fabsf(v0[j]), __builtin_fabsf(v1[j])));
      am = fmaxf(am, fmaxf(__builtin_fabsf(v2[j]), __builtin_fabsf(v3[j])));
    }
#pragma unroll
    for (int off = 32; off; off >>= 1) am = fmaxf(am, __shfl_xor(am, off));
    __shared__ float wm[4];
    if ((t & 63) == 0) wm[t >> 6] = am;
    __syncthreads();
    am = fmaxf(fmaxf(wm[0], wm[1]), fmaxf(wm[2], wm[3]));
    am = fmaxf(am, 1e-20f);
    const float qs = 127.0f / am;
    int q[16];
#pragma unroll
    for (int j = 0; j < 4; ++j) {
      q[j]      = (int)rintf(v0[j] * qs);
      q[4 + j]  = (int)rintf(v1[j] * qs);
      q[8 + j]  = (int)rintf(v2[j] * qs);
      q[12 + j] = (int)rintf(v3[j] * qs);
    }
    i32x4 pk;
#pragma unroll
    for (int j = 0; j < 4; ++j)
      pk[j] = (q[4*j] & 255) | ((q[4*j+1] & 255) << 8) |
              ((q[4*j+2] & 255) << 16) | ((q[4*j+3] & 255) << 24);
    *(i32x4*)(xq + (size_t)bid * KDIM + t * 16) = pk;
    if (t == 0) xs[bid] = am * (1.0f / 127.0f);
  } else {
    const int n = bid - MDIM;
    const int* row = w8 + (size_t)n * KDIM + t * 16;
    ix4 w0 = *(const ix4*)(row);
    ix4 w1 = *(const ix4*)(row + 4);
    ix4 w2 = *(const ix4*)(row + 8);
    ix4 w3 = *(const ix4*)(row + 12);
    i32x4 pk;
    pk[0] = (w0[0] & 255) | ((w0[1] & 255) << 8) | ((w0[2] & 255) << 16) | ((w0[3] & 255) << 24);
    pk[1] = (w1[0] & 255) | ((w1[1] & 255) << 8) | ((w1[2] & 255) << 16) | ((w1[3] & 255) << 24);
    pk[2] = (w2[0] & 255) | ((w2[1] & 255) << 8) | ((w2[2] & 255) << 16) | ((w2[3] & 255) << 24);
    pk[3] = (w3[0] & 255) | ((w3[1] & 255) << 8) | ((w3[2] & 255) << 16) | ((w3[3] & 255) << 24);
    *(i32x4*)(wq + (size_t)n * KDIM + t * 16) = pk;
  }
}

// ---------------- 256x256 int8 GEMM (R8/R13: validated counted-vmcnt) ----------------
// 512 threads = 8 waves (2M x 4N). Per-wave output 128x64. K-step = 64 i8.
// LDS = 2 dbuf x (256x64 A + 256x64 B) i8 = 64 KiB.
// mfma_i32_16x16x64_i8: per-lane A/B frag = 16 contiguous i8 (one b128):
//   lane l: row l&15, k = 16*(l>>4)+j. C/D: col=lane&15, row=(lane>>4)*4+reg
//   (dtype-independent, m121-128).
// Tile schedule (validated end-to-end in R8 + R13 green runs):
//   [boundary: read a0(4),b0(2) from cur]
//   Phase A: read b1(2),a1(4); 16 MFMA (a0 x {b0,b1}); lgkmcnt(0); BAR
//   Phase B: stage tile u+2 (4 gloads); 16 MFMA (a1 x {b0,b1});
//            vmcnt(4); BAR; read-ahead a0,b0 from nxt
// Region safety: all 12 ds_reads of cur drained by Phase-A lgkmcnt(0)+BAR
//   before any stage into cur; cur re-read only at tile u+2, gated by tile
//   u+1's vmcnt(4)+BAR. vmcnt ledger: entering u: 4 outstanding ((u+1)'s);
//   +4 in Phase B; vmcnt(4) leaves (u+2)'s. Tail u=NT-2: no stage, vmcnt(0).
// SESSION NOTES (do not "improve" without full re-validation):
//   - R10/R12: this schedule at 4-wave 256x128 geometry fails correctness
//     (incl. with sched_barrier(0)); only this 8-wave artifact is green.
//   - R14: 32x32x32 MFMA shape is structurally 4-way bank-conflicted here:
//     even rows always have bank-base 0 (r*16 mod 32 == 0), and a 32-row
//     fragment read spans 16 even rows over only 4 possible 16B slots ->
//     >=4 lanes/bank-run, no XOR can fix it at BK=64. 16x16x64 reads only
//     16 rows/instr -> 2-way = free. Measured: 6.29M conflicts, -12%.
// LDS bank swizzle for 64B rows: slot' = s^((row>>1)&3); staging pre-swizzle
//   ks = (l&3)^((l>>3)&3) on the GLOBAL source; linear gload_lds dest
//   (rule 21). Verified SQ_LDS_BANK_CONFLICT == 0.

__global__ __launch_bounds__(512, 2) void gemm_i8(
    const signed char* __restrict__ Aq,    // [M][K] i8
    const signed char* __restrict__ Wq,    // [N][K] i8
    const float* __restrict__ xs,          // [M] row scale = absmax/127
    const float* __restrict__ scales,      // [N]
    const float* __restrict__ bias,
    float* __restrict__ C) {
  __shared__ signed char Ash[2 * 16384];   // [2][256][64]
  __shared__ signed char Bsh[2 * 16384];

  const int tid = threadIdx.x;
  const int w   = tid >> 6;
  const int l   = tid & 63;
  const int wr  = w >> 2;            // 0..1 : M half
  const int wc  = w & 3;             // 0..3 : N quarter
  const int fr  = l & 15;
  const int fq  = l >> 4;

  // XCD-aware swizzle: 256 blocks, 256 % 8 == 0
  const int id  = blockIdx.x;
  const int swz = (id & 7) * 32 + (id >> 3);
  const int bm  = swz >> 4, bn = swz & 15;

  const signed char* aorg = Aq + (size_t)(bm * 256) * KDIM;
  const signed char* borg = Wq + (size_t)(bn * 256) * KDIM;

  // staging: wave covers 16 rows of 64B per gload; pre-swizzled global slot
  const int lr = l >> 2;                       // row-in-wave-chunk 0..15
  const int ks = (l & 3) ^ ((l >> 3) & 3);     // swizzled 16B slot
  const size_t g_off = (size_t)(w * 16 + lr) * KDIM + (size_t)ks * 16;
  const int    s_off = w * 1024;               // bytes, wave-uniform

#define STAGE(isB, t, h) do {                                                   \
    const signed char* _g = ((isB) ? borg : aorg)                               \
        + (size_t)(h) * 128 * KDIM + (size_t)(t) * 64 + g_off;                  \
    signed char* _l = ((isB) ? Bsh : Ash)                                       \
        + (((t) & 1) * 16384 + (h) * 8192 + s_off);                             \
    gload_lds16(_g, _l);                                                        \
  } while (0)

  // ds_read offsets (swizzled): row = (wr*128 | wc*64) + sub*16 + fr;
  // (row>>1)&3 == (fr>>1)&3 for all sub -> per-lane constant slot.
  const int arow = (wr * 128 + fr) * 64;
  const int brow = (wc * 64  + fr) * 64;
  const int sl   = (fq ^ ((fr >> 1) & 3)) * 16;

#define LDA(off, rb) (*(const i32x4*)(Ash + (off) + arow + (rb) * 1024 + sl))
#define LDB(off, nc) (*(const i32x4*)(Bsh + (off) + brow + (nc) * 1024 + sl))

#define BAR   __builtin_amdgcn_s_barrier()
#define LGKM0 asm volatile("s_waitcnt lgkmcnt(0)" ::: "memory")
#define VM4   asm volatile("s_waitcnt vmcnt(4)" ::: "memory")
#define VM0   asm volatile("s_waitcnt vmcnt(0)" ::: "memory")
#define NOVM  ((void)0)
#define SP1   __builtin_amdgcn_s_setprio(1)
#define SP0   __builtin_amdgcn_s_setprio(0)

  i32x4 acc[8][4] = {};
  i32x4 a0[4], a1[4], b0[2], b1[2];

#define READ_A0(CO) { _Pragma("unroll") for (int rb = 0; rb < 4; ++rb) a0[rb] = LDA(CO, rb); }
#define READ_A1(CO) { _Pragma("unroll") for (int rb = 0; rb < 4; ++rb) a1[rb] = LDA(CO, 4 + rb); }
#define READ_B0(CO) { _Pragma("unroll") for (int cb = 0; cb < 2; ++cb) b0[cb] = LDB(CO, cb); }
#define READ_B1(CO) { _Pragma("unroll") for (int cb = 0; cb < 2; ++cb) b1[cb] = LDB(CO, 2 + cb); }

#define MFMA_Q(MH, NH, AA, BB)                                                  \
  { _Pragma("unroll") for (int rb = 0; rb < 4; ++rb)                            \
    _Pragma("unroll") for (int cb = 0; cb < 2; ++cb)                            \
      mfma_i8(acc[(MH)*4+rb][(NH)*2+cb], AA[rb], BB[cb]); }

#define TILE(U, CO, NX, S2, VMST) do {                                          \
    const int _nx = (CO) ^ 16384;                                               \
    /* Phase A: pre-read b1,a1 ; MFMA a0 x {b0,b1} */                           \
    READ_B1(CO); READ_A1(CO);                                                   \
    SP1; MFMA_Q(0, 0, a0, b0); MFMA_Q(0, 1, a0, b1); SP0;                       \
    LGKM0; BAR;                                                                 \
    /* Phase B: stage (U+2) into cur ; MFMA a1 x {b0,b1} */                     \
    if (S2) { STAGE(0, (U) + 2, 0); STAGE(0, (U) + 2, 1);                       \
              STAGE(1, (U) + 2, 0); STAGE(1, (U) + 2, 1); }                     \
    SP1; MFMA_Q(1, 0, a1, b0); MFMA_Q(1, 1, a1, b1); SP0;                       \
    VMST; BAR;                                                                  \
    if (NX) { READ_A0(_nx); READ_B0(_nx); }                                     \
  } while (0)

  // ---- prologue: stage t0 + t1 (8 gloads), land t0, boundary read ----
  STAGE(0, 0, 0); STAGE(0, 0, 1); STAGE(1, 0, 0); STAGE(1, 0, 1);
  STAGE(0, 1, 0); STAGE(0, 1, 1); STAGE(1, 1, 0); STAGE(1, 1, 1);
  VM4;   // t0 landed; t1's 4 in flight = steady-state entry
  BAR;
  READ_A0(0); READ_B0(0);

#pragma unroll 2
  for (int u = 0; u < NT - 2; ++u) {
    const int cur = (u & 1) * 16384;
    TILE(u, cur, 1, 1, VM4);
  }
  TILE(NT - 2, 0,     1, 0, VM0);
  TILE(NT - 1, 16384, 0, 0, NOVM);

#undef TILE
#undef MFMA_Q
#undef READ_A0
#undef READ_A1
#undef READ_B0
#undef READ_B1
#undef STAGE
#undef LDA
#undef LDB

  // ---- epilogue: out = acc * xs[m] * (scales[n]/127) + bias[n] ----
  const float inv127 = 1.0f / 127.0f;
  const int n_base = bn * 256 + wc * 64;
  const int m_base = bm * 256 + wr * 128 + fq * 4;
  float xr[8][4];
#pragma unroll
  for (int rb = 0; rb < 8; ++rb)
#pragma unroll
    for (int r = 0; r < 4; ++r) xr[rb][r] = xs[m_base + rb * 16 + r];
#pragma unroll
  for (int nc = 0; nc < 4; ++nc) {
    const int n = n_base + nc * 16 + fr;
    const float sw = scales[n] * inv127;
    const float bz = bias[n];
#pragma unroll
    for (int rb = 0; rb < 8; ++rb) {
      float* cp = C + (size_t)(m_base + rb * 16) * NDIM + n;
#pragma unroll
      for (int r = 0; r < 4; ++r)
        cp[(size_t)r * NDIM] = (float)acc[rb][nc][r] * (xr[rb][r] * sw) + bz;
    }
  }
}

// ---------------- fallback: fused conversion, reg staging (128^2 bf16) ----------------

__global__ __launch_bounds__(256) void gemm_fused(
    const float* __restrict__ X,
    const int* __restrict__ W,
    const float* __restrict__ scales,
    const float* __restrict__ bias,
    float* __restrict__ C) {
  __shared__ unsigned short As[128 * 32];
  __shared__ unsigned short Bs[128 * 32];

  const int tid = threadIdx.x;
  const int lane = tid & 63;
  const int wave = tid >> 6;
  const int wr = wave >> 1, wc = wave & 1;
  const int fr = lane & 15, fq = lane >> 4;

  int id = blockIdx.x;
  int swz = (id & 7) * 128 + (id >> 3);
  const int bm = swz >> 5, bn = swz & 31;

  const int r0 = tid >> 2;
  const int kc = (tid & 3) * 8;
  const size_t aBase = (size_t)(bm * 128 + r0) * KDIM + kc;
  const size_t bBase = (size_t)(bn * 128 + r0) * KDIM + kc;

  f32x4 acc[4][4] = {};

  for (int k0 = 0; k0 < KDIM; k0 += 32) {
    const float* xp = X + aBase + k0;
    const int*   wp = W + bBase + k0;
    fx4 x0 = *(const fx4*)xp;
    fx4 x1 = *(const fx4*)(xp + 4);
    fx4 x2 = *(const fx4*)(xp + (size_t)64 * KDIM);
    fx4 x3 = *(const fx4*)(xp + (size_t)64 * KDIM + 4);
    ix4 w0 = *(const ix4*)wp;
    ix4 w1 = *(const ix4*)(wp + 4);
    ix4 w2 = *(const ix4*)(wp + (size_t)64 * KDIM);
    ix4 w3 = *(const ix4*)(wp + (size_t)64 * KDIM + 4);

    usx8 ca, cb, cc, cd;
#pragma unroll
    for (int j = 0; j < 4; ++j) {
      ca[j] = f32_to_bf16_rne(x0[j]);  ca[j + 4] = f32_to_bf16_rne(x1[j]);
      cb[j] = f32_to_bf16_rne(x2[j]);  cb[j + 4] = f32_to_bf16_rne(x3[j]);
      cc[j] = f32_to_bf16_rne((float)w0[j]); cc[j + 4] = f32_to_bf16_rne((float)w1[j]);
      cd[j] = f32_to_bf16_rne((float)w2[j]); cd[j + 4] = f32_to_bf16_rne((float)w3[j]);
    }

    __syncthreads();
    *reinterpret_cast<usx8*>(As + tid * 8)        = ca;
    *reinterpret_cast<usx8*>(As + 2048 + tid * 8) = cb;
    *reinterpret_cast<usx8*>(Bs + tid * 8)        = cc;
    *reinterpret_cast<usx8*>(Bs + 2048 + tid * 8) = cd;
    __syncthreads();

    bf16x8 af[4], bfr[4];
    const unsigned short* ap = As + (wr * 64 + fr) * 32 + fq * 8;
    const unsigned short* bp = Bs + (wc * 64 + fr) * 32 + fq * 8;
#pragma unroll
    for (int i = 0; i < 4; ++i) {
      af[i]  = *reinterpret_cast<const bf16x8*>(ap + i * 512);
      bfr[i] = *reinterpret_cast<const bf16x8*>(bp + i * 512);
    }
#pragma unroll
    for (int im = 0; im < 4; ++im)
#pragma unroll
      for (int in_ = 0; in_ < 4; ++in_)
        acc[im][in_] = __builtin_amdgcn_mfma_f32_16x16x32_bf16(
            af[im], bfr[in_], acc[im][in_], 0, 0, 0);
  }

  const float inv127 = 1.0f / 127.0f;
#pragma unroll
  for (int in_ = 0; in_ < 4; ++in_) {
    int n = bn * 128 + wc * 64 + in_ * 16 + fr;
    float sc = scales[n] * inv127;
    float bz = bias[n];
#pragma unroll
    for (int im = 0; im < 4; ++im) {
      int m0 = bm * 128 + wr * 64 + im * 16 + fq * 4;
      float* cp = C + (size_t)m0 * NDIM + n;
#pragma unroll
      for (int r = 0; r < 4; ++r)
        cp[(size_t)r * NDIM] = acc[im][in_][r] * sc + bz;
    }
  }
}

// ---------------- host launch ----------------

extern "C" void kernel_launch(void* const* d_in, const int* in_sizes, int n_in,
                              void* d_out, int out_size, void* d_ws, size_t ws_size,
                              hipStream_t stream) {
  const float* x      = (const float*)d_in[0];
  const int*   w8     = (const int*)d_in[1];
  const float* scales = (const float*)d_in[2];
  // d_in[3] = weight_fp : unused by the reference
  const float* bias   = (const float*)d_in[4];
  float* out = (float*)d_out;

  const size_t xq_bytes = (size_t)MDIM * KDIM;           // 16.7 MB
  const size_t wq_bytes = (size_t)NDIM * KDIM;           // 16.7 MB
  const size_t xs_bytes = (size_t)MDIM * sizeof(float);
  const size_t need = xq_bytes + wq_bytes + xs_bytes;

  if (ws_size >= need) {
    signed char* xq = (signed char*)d_ws;
    signed char* wq = xq + xq_bytes;
    float*       xs = (float*)(wq + wq_bytes);
    quant_both<<<MDIM + NDIM, 256, 0, stream>>>(x, w8, xq, wq, xs);
    gemm_i8<<<256, 512, 0, stream>>>(xq, wq, xs, scales, bias, out);
  } else {
    gemm_fused<<<1024, 256, 0, stream>>>(x, w8, scales, bias, out);
  }
}